// Round 9
// baseline (1255.556 us; speedup 1.0000x reference)
//
#include <hip/hip_runtime.h>
#include <hip/hip_bf16.h>
#include <stdint.h>

#define DM 1024
#define DH 4096
#define DV 32000
#define NC 2048
#define NL 8

typedef float f32x4_t __attribute__((ext_vector_type(4)));
typedef __bf16 bf16x8_t __attribute__((ext_vector_type(8)));
typedef unsigned short u16x4_t __attribute__((ext_vector_type(4)));
typedef unsigned short u16x8_t __attribute__((ext_vector_type(8)));

typedef __attribute__((address_space(1))) void as1_void;
typedef __attribute__((address_space(3))) void as3_void;

__device__ __forceinline__ unsigned short f2bf(float f) {
  unsigned int u = __builtin_bit_cast(unsigned int, f);
  u += 0x7fffu + ((u >> 16) & 1u);  // round-to-nearest-even
  return (unsigned short)(u >> 16);
}

__device__ __forceinline__ void gload_lds16(const void* g, void* l) {
  __builtin_amdgcn_global_load_lds((as1_void*)(void*)g, (as3_void*)l, 16, 0, 0);
}

// grid-stride f32->bf16 cast tail segment: cidx in [0,512), 256 threads.
// Covers [0,n) in 8-elem chunks; n must be a multiple of 8.
__device__ __forceinline__ void cast_tail8(const float* __restrict__ src,
                                           unsigned short* __restrict__ dst,
                                           size_t n, int cidx, int tid) {
  for (size_t i = (size_t)cidx * 2048 + (size_t)tid * 8; i < n;
       i += (size_t)512 * 2048) {
    const float4 a = *reinterpret_cast<const float4*>(src + i);
    const float4 b = *reinterpret_cast<const float4*>(src + i + 4);
    u16x8_t v;
    v[0] = f2bf(a.x); v[1] = f2bf(a.y); v[2] = f2bf(a.z); v[3] = f2bf(a.w);
    v[4] = f2bf(b.x); v[5] = f2bf(b.y); v[6] = f2bf(b.z); v[7] = f2bf(b.w);
    *reinterpret_cast<u16x8_t*>(dst + i) = v;
  }
}

// ---------------------------------------------------------------------------
// NT bf16 MFMA GEMM body: C[M][N] = A[M][K] * Bt[N][K]^T, one 128xBN tile.
// BM=128, BN=64, BK=64, 256 threads (4 waves 2x2), wave tile 64x32.
// Chunk swizzle ^(r&7): measured 0 bank conflicts. Caller owns decode + LDS.
// NOTE r1/r2: BN=128 via 4-wave (152 regs, occupancy cliff) and via 8-wave
// 512thr both failed to beat this: structure is latency-bound on the
// vmcnt(0)+barrier drain, not tile-shape-bound. Keep BN=64.
// NOTE r4: OV reassociation P@(x@wov) FAILED absmax (0.176 > 0.164) —
// moving the bf16 quantization onto v=x@wov amplifies through P. Do not.
// NOTE r7: K-chain REASSOCIATION (down split 4->2, scores split2->fullK)
// FAILED absmax (0.197 > 0.164) despite no structural bug — bf16 rounding
// flips at f2bf boundaries compound through 8 layers. Only BIT-IDENTICAL
// transforms are safe; keep down split-4 + scores split-2 as verified.
// NOTE r8: skipping layer-7 x/xT stores (analysis: bit-identical) passed the
// first check but DIVERGED after graph-replay timing (2.5 absmax). No
// store-skip edits on persistent buffers without on-box debugging.
// ---------------------------------------------------------------------------
template <int BNT, bool B_FP32, bool SPLIT, bool CAUSAL, bool CAUSAL_K,
          bool HAS_BIAS, bool RELU, bool OUT_BF16>
__device__ __forceinline__ void gemm_body(
    unsigned short* As, unsigned short* Bs, const unsigned short* __restrict__ A,
    const void* __restrict__ Bt, const float* __restrict__ bias,
    void* __restrict__ Cout, int M, int N, int lda, int Ks, int bx, int by,
    int koff, int zslice) {
  constexpr int BK = 64;
  constexpr int BN = BNT;
  constexpr int CPTA = 4;
  constexpr int CPTB = (BN * BK) / 2048;
  constexpr int NF = BN / 32;
  const int t = threadIdx.x;
  const int lane = t & 63;
  const int wid = t >> 6;
  const int wr = wid >> 1, wc = wid & 1;
  const int row0 = by * 128;
  const int col0 = bx * BN;

  if constexpr (CAUSAL) {
    if (col0 > row0 + 127) return;  // fully-masked tile (uniform exit)
  }

  int Kend = Ks;
  if constexpr (CAUSAL_K) {
    const int need = row0 + 128 - koff;  // need k < row0+128 (P lower-tri)
    Kend = need <= 0 ? 0 : (need >= Ks ? Ks : ((need + BK - 1) & ~(BK - 1)));
    if constexpr (SPLIT) {
      if (Kend <= 0) return;  // partials are exact zeros; consumer skips them
    }
  }

  f32x4_t acc[4][NF];
#pragma unroll
  for (int m = 0; m < 4; m++)
#pragma unroll
    for (int n = 0; n < NF; n++) acc[m][n] = (f32x4_t){0.f, 0.f, 0.f, 0.f};

  for (int kt = 0; kt < Kend; kt += BK) {
    __syncthreads();
    // ---- stage A: 128x64 bf16, 4 chunks per thread ----
#pragma unroll
    for (int i = 0; i < CPTA; i++) {
      const int c = i * 256 + t;
      const int r = c >> 3;
      const int ko = ((c & 7) ^ (r & 7)) * 8;  // pre-swizzled source chunk
      const unsigned short* g = A + (size_t)(row0 + r) * lda + koff + kt + ko;
      unsigned short* l = &As[(size_t)(i * 256 + wid * 64) * 8];  // wave-uniform
      gload_lds16(g, l);
    }
    // ---- stage B: BNx64 bf16 ----
    if constexpr (B_FP32) {
      const float* Bf = (const float*)Bt;
#pragma unroll
      for (int i = 0; i < CPTB; i++) {
        const int c = i * 256 + t;
        const int r = c >> 3;
        const int ko = ((c & 7) ^ (r & 7)) * 8;
        const float* g = Bf + (size_t)(col0 + r) * lda + koff + kt + ko;
        const float4 f0 = *reinterpret_cast<const float4*>(g);
        const float4 f1 = *reinterpret_cast<const float4*>(g + 4);
        u16x8_t v;
        v[0] = f2bf(f0.x); v[1] = f2bf(f0.y); v[2] = f2bf(f0.z); v[3] = f2bf(f0.w);
        v[4] = f2bf(f1.x); v[5] = f2bf(f1.y); v[6] = f2bf(f1.z); v[7] = f2bf(f1.w);
        *reinterpret_cast<u16x8_t*>(&Bs[(size_t)c * 8]) = v;
      }
    } else {
      const unsigned short* Bu = (const unsigned short*)Bt;
#pragma unroll
      for (int i = 0; i < CPTB; i++) {
        const int c = i * 256 + t;
        const int r = c >> 3;
        const int ko = ((c & 7) ^ (r & 7)) * 8;
        const unsigned short* g = Bu + (size_t)(col0 + r) * lda + koff + kt + ko;
        unsigned short* l = &Bs[(size_t)(i * 256 + wid * 64) * 8];
        gload_lds16(g, l);
      }
    }
    __syncthreads();

    // ---- fragments + MFMA (2 k-slices of 32, ascending k) ----
#pragma unroll
    for (int kk = 0; kk < 2; kk++) {
      bf16x8_t av[4], bv[NF];
#pragma unroll
      for (int m = 0; m < 4; m++) {
        const int arow = wr * 64 + m * 16 + (lane & 15);
        const int akc = (kk * 4 + (lane >> 4)) ^ (arow & 7);
        av[m] = __builtin_bit_cast(
            bf16x8_t, *reinterpret_cast<const u16x8_t*>(&As[arow * BK + akc * 8]));
      }
#pragma unroll
      for (int n = 0; n < NF; n++) {
        const int brow = wc * (BN / 2) + n * 16 + (lane & 15);
        const int bkc = (kk * 4 + (lane >> 4)) ^ (brow & 7);
        bv[n] = __builtin_bit_cast(
            bf16x8_t, *reinterpret_cast<const u16x8_t*>(&Bs[brow * BK + bkc * 8]));
      }
#pragma unroll
      for (int m = 0; m < 4; m++)
#pragma unroll
        for (int n = 0; n < NF; n++)
          acc[m][n] = __builtin_amdgcn_mfma_f32_16x16x32_bf16(av[m], bv[n],
                                                              acc[m][n], 0, 0, 0);
    }
  }

  // ---- epilogue: C/D layout col=lane&15, row=(lane>>4)*4+j ----
#pragma unroll
  for (int m = 0; m < 4; m++) {
    const int rbase = row0 + wr * 64 + m * 16 + (lane >> 4) * 4;
#pragma unroll
    for (int n = 0; n < NF; n++) {
      const int col = col0 + wc * (BN / 2) + n * 16 + (lane & 15);
      if constexpr (SPLIT) {
        float* out = (float*)Cout + (size_t)zslice * M * N;
#pragma unroll
        for (int j = 0; j < 4; j++)
          out[(size_t)(rbase + j) * N + col] = acc[m][n][j];
      } else {
        float bval = 0.0f;
        if constexpr (HAS_BIAS) bval = bias[col];
#pragma unroll
        for (int j = 0; j < 4; j++) {
          float v = acc[m][n][j];
          if constexpr (HAS_BIAS) v += bval;
          if constexpr (RELU) v = fmaxf(v, 0.0f);
          const size_t idx = (size_t)(rbase + j) * N + col;
          if constexpr (OUT_BF16)
            ((unsigned short*)Cout)[idx] = f2bf(v);
          else
            __builtin_nontemporal_store(v, (float*)Cout + idx);
        }
      }
    }
  }
}

// 4x4 super-tile decode on a linear id over (GX x GY) tiles, column-major
// supers (requires GX%4==0 && GY%4==0).
__device__ __forceinline__ void super_decode(int idx, int gy, int& bx, int& by) {
  const int s = idx >> 4;
  const int u = idx & 15;
  const int sgy = gy >> 2;
  const int sx = s / sgy;
  const int sy = s - sx * sgy;
  bx = sx * 4 + (u & 3);
  by = sy * 4 + (u >> 2);
}

// ---------------------------------------------------------------------------
// standalone GEMM wrapper (decode: m204 XCD chunk + 4x4 super-tile)
// ---------------------------------------------------------------------------
template <int BNT, bool B_FP32, bool SPLIT, bool CAUSAL, bool CAUSAL_K,
          bool HAS_BIAS, bool RELU, bool OUT_BF16>
__global__ __launch_bounds__(256) void gemm_nt(
    const unsigned short* __restrict__ A, const void* __restrict__ Bt,
    const float* __restrict__ bias, void* __restrict__ Cout, int M, int N,
    int lda, int Ks) {
  __shared__ __attribute__((aligned(16))) unsigned short As[128 * 64];
  __shared__ __attribute__((aligned(16))) unsigned short Bs[BNT * 64];
  const int gx = gridDim.x, gy = gridDim.y;
  const int nwg = gx * gy;
  const int orig = blockIdx.y * gx + blockIdx.x;
  const int qq = nwg >> 3, rr = nwg & 7;
  const int xc = orig & 7, ii = orig >> 3;
  const int wgid = (xc < rr ? xc * (qq + 1) : rr * (qq + 1) + (xc - rr) * qq) + ii;
  int bx, by;
  super_decode(wgid, gy, bx, by);
  gemm_body<BNT, B_FP32, SPLIT, CAUSAL, CAUSAL_K, HAS_BIAS, RELU, OUT_BF16>(
      As, Bs, A, Bt, bias, Cout, M, N, lda, Ks, bx, by,
      SPLIT ? blockIdx.z * Ks : 0, blockIdx.z);
}

// ---------------------------------------------------------------------------
// ov GEMM + fused residual: C = ab @ wovT^T (full K=DM), then
// v = C + x + b_down + sum4(dpart); writes x (f32), xb (bf16), xT (bf16^T).
// Grid 16x16 (tiles of 128x64). xT store: acc j-index walks rows at fixed
// col -> 4 consecutive u16 at xT[col*NC + rbase], one u16x4 store.
// (r8: do NOT skip the layer-7 x/xT stores — replay divergence.)
// ---------------------------------------------------------------------------
__global__ __launch_bounds__(256) void gemm_ov_res(
    const unsigned short* __restrict__ A, const unsigned short* __restrict__ Bt,
    float* __restrict__ x, unsigned short* __restrict__ xb,
    unsigned short* __restrict__ xT, const float* __restrict__ dp,
    const float* __restrict__ bd) {
  __shared__ __attribute__((aligned(16))) unsigned short As[128 * 64];
  __shared__ __attribute__((aligned(16))) unsigned short Bs[64 * 64];
  const int gx = gridDim.x, gy = gridDim.y;
  const int nwg = gx * gy;
  const int orig = blockIdx.y * gx + blockIdx.x;
  const int qq = nwg >> 3, rr = nwg & 7;
  const int xc = orig & 7, ii = orig >> 3;
  const int wgid = (xc < rr ? xc * (qq + 1) : rr * (qq + 1) + (xc - rr) * qq) + ii;
  int bx, by;
  super_decode(wgid, gy, bx, by);

  const int t = threadIdx.x;
  const int lane = t & 63;
  const int wid = t >> 6;
  const int wr = wid >> 1, wc = wid & 1;
  const int row0 = by * 128;
  const int col0 = bx * 64;

  f32x4_t acc[4][2];
#pragma unroll
  for (int m = 0; m < 4; m++)
#pragma unroll
    for (int n = 0; n < 2; n++) acc[m][n] = (f32x4_t){0.f, 0.f, 0.f, 0.f};

  for (int kt = 0; kt < DM; kt += 64) {
    __syncthreads();
#pragma unroll
    for (int i = 0; i < 4; i++) {
      const int c = i * 256 + t;
      const int r = c >> 3;
      const int ko = ((c & 7) ^ (r & 7)) * 8;
      const unsigned short* g = A + (size_t)(row0 + r) * DM + kt + ko;
      unsigned short* l = &As[(size_t)(i * 256 + wid * 64) * 8];
      gload_lds16(g, l);
    }
#pragma unroll
    for (int i = 0; i < 2; i++) {
      const int c = i * 256 + t;
      const int r = c >> 3;
      const int ko = ((c & 7) ^ (r & 7)) * 8;
      const unsigned short* g = Bt + (size_t)(col0 + r) * DM + kt + ko;
      unsigned short* l = &Bs[(size_t)(i * 256 + wid * 64) * 8];
      gload_lds16(g, l);
    }
    __syncthreads();

#pragma unroll
    for (int kk = 0; kk < 2; kk++) {
      bf16x8_t av[4], bv[2];
#pragma unroll
      for (int m = 0; m < 4; m++) {
        const int arow = wr * 64 + m * 16 + (lane & 15);
        const int akc = (kk * 4 + (lane >> 4)) ^ (arow & 7);
        av[m] = __builtin_bit_cast(
            bf16x8_t, *reinterpret_cast<const u16x8_t*>(&As[arow * 64 + akc * 8]));
      }
#pragma unroll
      for (int n = 0; n < 2; n++) {
        const int brow = wc * 32 + n * 16 + (lane & 15);
        const int bkc = (kk * 4 + (lane >> 4)) ^ (brow & 7);
        bv[n] = __builtin_bit_cast(
            bf16x8_t, *reinterpret_cast<const u16x8_t*>(&Bs[brow * 64 + bkc * 8]));
      }
#pragma unroll
      for (int m = 0; m < 4; m++)
#pragma unroll
        for (int n = 0; n < 2; n++)
          acc[m][n] = __builtin_amdgcn_mfma_f32_16x16x32_bf16(av[m], bv[n],
                                                              acc[m][n], 0, 0, 0);
    }
  }

  const size_t nMD = (size_t)NC * DM;
#pragma unroll
  for (int m = 0; m < 4; m++) {
    const int rbase = row0 + wr * 64 + m * 16 + (lane >> 4) * 4;
#pragma unroll
    for (int n = 0; n < 2; n++) {
      const int col = col0 + wc * 32 + n * 16 + (lane & 15);
      const float bval = bd[col];
      u16x4_t ot;
#pragma unroll
      for (int j = 0; j < 4; j++) {
        const size_t idx = (size_t)(rbase + j) * DM + col;
        float v = acc[m][n][j] + x[idx] + bval;
#pragma unroll
        for (int s = 0; s < 4; s++) v += dp[(size_t)s * nMD + idx];
        x[idx] = v;
        const unsigned short o = f2bf(v);
        xb[idx] = o;
        ot[j] = o;
      }
      *reinterpret_cast<u16x4_t*>(&xT[(size_t)col * NC + rbase]) = ot;
    }
  }
}

// ---------------------------------------------------------------------------
// fused up + q + weight-cast + next-layer wqk/wov transpose: 2048 blocks,
// chunks of 256/XCD = 128 up + 32 q + 64 cast + 32 transpose.
// up: h1 = relu(xb @ wup^T + b_up)  [2048,4096]; WUP32: layer-0 reads w_up
//     fp32 directly (in-stage f2bf = bit-identical to pre-cast).
// q:  qb = bf16(xb @ wqkT_l)        [2048,1024], K=1024 full.
// cast: streams next-layer w_up + tok slice under the GEMMs' BW slack.
// transpose: wqkT/wovT for layer l+1 (fp32 [1024][1024] -> bf16 transposed);
//     consumers are in later launches (stream order guarantees readiness).
// ---------------------------------------------------------------------------
template <bool WUP32>
__global__ __launch_bounds__(256) void fused_up_q(
    const unsigned short* __restrict__ xb, const void* __restrict__ wup,
    const float* __restrict__ bup, unsigned short* __restrict__ h1,
    const unsigned short* __restrict__ wqkT, unsigned short* __restrict__ qb,
    const float* __restrict__ c0s, unsigned short* __restrict__ c0d, size_t c0n,
    const float* __restrict__ c1s, unsigned short* __restrict__ c1d, size_t c1n,
    const float* __restrict__ tr0s, unsigned short* __restrict__ tr0d,
    const float* __restrict__ tr1s, unsigned short* __restrict__ tr1d) {
  __shared__ __attribute__((aligned(16))) unsigned short As[128 * 64];
  __shared__ __attribute__((aligned(16))) unsigned short Bs[64 * 64];
  const int orig = blockIdx.x;          // nwg = 2048, %8 == 0
  const int xc = orig & 7, ii = orig >> 3;  // chunk = xc, local ii in [0,256)
  int bx, by;
  if (ii < 128) {
    const int idx = xc * 128 + ii;      // [0,1024) bijective
    super_decode(idx, 16, bx, by);      // gy=16 (grid 64x16)
    gemm_body<64, WUP32, false, false, false, true, true, true>(
        As, Bs, xb, wup, bup, h1, NC, DH, DM, DM, bx, by, 0, 0);
  } else if (ii < 160) {
    const int idx = xc * 32 + (ii - 128);  // [0,256) bijective
    super_decode(idx, 16, bx, by);         // gy=16 (grid 16x16)
    gemm_body<64, false, false, false, false, false, false, true>(
        As, Bs, xb, wqkT, nullptr, qb, NC, DM, DM, DM, bx, by, 0, 0);
  } else if (ii < 224) {
    const int cidx = xc * 64 + (ii - 160);  // [0,512) bijective
    cast_tail8(c0s, c0d, c0n, cidx, threadIdx.x);
    cast_tail8(c1s, c1d, c1n, cidx, threadIdx.x);
  } else {
    if (tr0s == nullptr) return;
    float* tf = (float*)As;               // 32x33 f32 tile (4224 B, fits 16K)
    const int tb = xc * 32 + (ii - 224);  // [0,256) bijective
    const int tx = threadIdx.x & 31;
    const int ty = threadIdx.x >> 5;      // 0..7
#pragma unroll 1
    for (int jj = 0; jj < 8; jj++) {
      const int j = tb * 8 + jj;          // [0,2048): 2 matrices x 1024 tiles
      const float* src = (j < 1024) ? tr0s : tr1s;
      unsigned short* dst = (j < 1024) ? tr0d : tr1d;
      const int tile = j & 1023;
      const int tX = tile & 31, tY = tile >> 5;
      __syncthreads();
#pragma unroll
      for (int i = 0; i < 4; i++) {
        const int r = ty + i * 8;
        tf[r * 33 + tx] = src[(size_t)(tY * 32 + r) * DM + tX * 32 + tx];
      }
      __syncthreads();
#pragma unroll
      for (int i = 0; i < 4; i++) {
        const int r = ty + i * 8;
        dst[(size_t)(tX * 32 + r) * DM + tY * 32 + tx] = f2bf(tf[tx * 33 + r]);
      }
    }
  }
}

// ---------------------------------------------------------------------------
// fused down + scores + weight-cast: 2560 blocks, 320/XCD =
//   128 down-gemm + 128 scores-gemm + 64 cast.
// down:   dpart[z] = h1 @ wdown-slice [2048,1024] split 4; WDN32: layer-0
//         reads w_down fp32 directly (bit-identical).
// scores: spool[z] = qb @ xb^T-slice  [2048,2048] split 2, causal tile-skip.
// (r7 lesson: do NOT change these split factors — reassociation fails absmax.)
// ---------------------------------------------------------------------------
template <bool WDN32>
__global__ __launch_bounds__(256) void fused_down_sc(
    const unsigned short* __restrict__ h1, const void* __restrict__ wdown,
    float* __restrict__ dpart, const unsigned short* __restrict__ qb,
    const unsigned short* __restrict__ xbv, float* __restrict__ spool,
    const float* __restrict__ c0s, unsigned short* __restrict__ c0d, size_t c0n,
    const float* __restrict__ c1s, unsigned short* __restrict__ c1d, size_t c1n) {
  __shared__ __attribute__((aligned(16))) unsigned short As[128 * 64];
  __shared__ __attribute__((aligned(16))) unsigned short Bs[64 * 64];
  const int orig = blockIdx.x;          // nwg = 2560, %8 == 0
  const int xc = orig & 7, ii = orig >> 3;  // chunk = xc, local ii in [0,320)
  if (ii < 128) {
    const int idx = xc * 128 + ii;      // [0,1024)
    const int z = idx >> 8;
    int bx, by;
    super_decode(idx & 255, 16, bx, by);
    gemm_body<64, WDN32, true, false, false, false, false, false>(
        As, Bs, h1, wdown, nullptr, dpart, NC, DM, DH, DH / 4, bx, by,
        z * (DH / 4), z);
  } else if (ii < 256) {
    const int idx = xc * 128 + (ii - 128);  // [0,1024)
    const int z = idx >> 9;
    int bx, by;
    super_decode(idx & 511, 16, bx, by);    // gy=16 (grid 32x16 per z)
    gemm_body<64, false, true, true, false, false, false, false>(
        As, Bs, qb, xbv, nullptr, spool, NC, NC, DM, DM / 2, bx, by,
        z * (DM / 2), z);
  } else {
    const int cidx = xc * 64 + (ii - 256);  // [0,512) bijective
    cast_tail8(c0s, c0d, c0n, cidx, threadIdx.x);
    cast_tail8(c1s, c1d, c1n, cidx, threadIdx.x);
  }
}

// ---------------------------------------------------------------------------
// three independent f32->bf16 casts in one launch (fallback path only)
__global__ __launch_bounds__(256) void cast3_f32_bf16(
    const float* __restrict__ in0, unsigned short* __restrict__ out0, size_t n0,
    const float* __restrict__ in1, unsigned short* __restrict__ out1, size_t n1,
    const float* __restrict__ in2, unsigned short* __restrict__ out2, size_t n2,
    int gper) {
  const int seg = blockIdx.x / gper;
  const int lb = blockIdx.x - seg * gper;
  const float* in = seg == 0 ? in0 : (seg == 1 ? in1 : in2);
  unsigned short* out = seg == 0 ? out0 : (seg == 1 ? out1 : out2);
  const size_t n = seg == 0 ? n0 : (seg == 1 ? n1 : n2);
  const size_t stride = (size_t)gper * 256 * 8;
  for (size_t i = ((size_t)lb * 256 + threadIdx.x) * 8; i < n; i += stride) {
    const float4 a = *reinterpret_cast<const float4*>(in + i);
    const float4 b = *reinterpret_cast<const float4*>(in + i + 4);
    u16x8_t v;
    v[0] = f2bf(a.x); v[1] = f2bf(a.y); v[2] = f2bf(a.z); v[3] = f2bf(a.w);
    v[4] = f2bf(b.x); v[5] = f2bf(b.y); v[6] = f2bf(b.z); v[7] = f2bf(b.w);
    *reinterpret_cast<u16x8_t*>(out + i) = v;
  }
}

// vectorized embed
__global__ __launch_bounds__(256) void embed_kernel(
    const int* __restrict__ tokens, const float* __restrict__ tok_emb,
    const float* __restrict__ pos_emb, float* __restrict__ x,
    unsigned short* __restrict__ xb) {
  const int i = blockIdx.x;
  const int tok = tokens[i];
  const float* te = tok_emb + (size_t)tok * DM;
  const float* pe = pos_emb + (size_t)i * DM;
  float* xr = x + (size_t)i * DM;
  unsigned short* xbr = xb + (size_t)i * DM;
  const int j = threadIdx.x * 4;
  const float4 a = *reinterpret_cast<const float4*>(te + j);
  const float4 b = *reinterpret_cast<const float4*>(pe + j);
  float4 v;
  v.x = a.x + b.x; v.y = a.y + b.y; v.z = a.z + b.z; v.w = a.w + b.w;
  *reinterpret_cast<float4*>(xr + j) = v;
  u16x4_t o;
  o[0] = f2bf(v.x); o[1] = f2bf(v.y); o[2] = f2bf(v.z); o[3] = f2bf(v.w);
  *reinterpret_cast<u16x4_t*>(xbr + j) = o;
}

// fp32 [z][R][C] -> bf16 [z][C][R]; two tensors in one launch
__global__ void transpose_cast_dual(const float* __restrict__ in0,
                                    unsigned short* __restrict__ out0,
                                    const float* __restrict__ in1,
                                    unsigned short* __restrict__ out1, int R,
                                    int C, int ZSPLIT) {
  __shared__ float tile[32][33];
  const int z = blockIdx.z;
  const float* in = (z < ZSPLIT) ? in0 : in1;
  unsigned short* out = (z < ZSPLIT) ? out0 : out1;
  const int zl = (z < ZSPLIT) ? z : z - ZSPLIT;
  const size_t lo = (size_t)zl * R * C;
  const int x = blockIdx.x * 32 + threadIdx.x;
#pragma unroll
  for (int i = threadIdx.y; i < 32; i += 8) {
    const int y = blockIdx.y * 32 + i;
    tile[i][threadIdx.x] = in[lo + (size_t)y * C + x];
  }
  __syncthreads();
  const int ox = blockIdx.y * 32 + threadIdx.x;
#pragma unroll
  for (int i = threadIdx.y; i < 32; i += 8) {
    const int oy = blockIdx.x * 32 + i;
    out[lo + (size_t)oy * R + ox] = f2bf(tile[threadIdx.x][i]);
  }
}

// bf16 [R][C] -> bf16 [C][R]  (layer-0 xT + fallback)
__global__ void transpose_u16(const unsigned short* __restrict__ in,
                              unsigned short* __restrict__ out, int R, int C) {
  __shared__ unsigned short tile[32][33];
  const int x = blockIdx.x * 32 + threadIdx.x;
#pragma unroll
  for (int i = threadIdx.y; i < 32; i += 8) {
    const int y = blockIdx.y * 32 + i;
    tile[i][threadIdx.x] = in[(size_t)y * C + x];
  }
  __syncthreads();
  const int ox = blockIdx.y * 32 + threadIdx.x;
#pragma unroll
  for (int i = threadIdx.y; i < 32; i += 8) {
    const int oy = blockIdx.x * 32 + i;
    out[(size_t)oy * R + ox] = tile[threadIdx.x][i];
  }
}

// causal softmax over sum of 2 fp32 partial slices; row staged in LDS.
__global__ __launch_bounds__(256) void softmax_split2(
    const float* __restrict__ p0, const float* __restrict__ p1,
    unsigned short* __restrict__ P, int n) {
  __shared__ float srow[NC];
  __shared__ float sred[4];
  const int i = blockIdx.x;
  const int valid = i + 1;
  const int wlimit = (i & ~127) + 128;
  const int t = threadIdx.x;
  const int wid = t >> 6, lane = t & 63;
  const size_t ro = (size_t)i * n;
  for (int j = t; j < valid; j += 256) srow[j] = p0[ro + j] + p1[ro + j];
  __syncthreads();

  float m = -3.0e38f;
  for (int j = t; j < valid; j += 256) m = fmaxf(m, srow[j]);
#pragma unroll
  for (int o = 32; o > 0; o >>= 1) m = fmaxf(m, __shfl_xor(m, o, 64));
  if (lane == 0) sred[wid] = m;
  __syncthreads();
  m = fmaxf(fmaxf(sred[0], sred[1]), fmaxf(sred[2], sred[3]));
  __syncthreads();

  float s = 0.f;
  for (int j = t; j < valid; j += 256) s += __expf(srow[j] - m);
#pragma unroll
  for (int o = 32; o > 0; o >>= 1) s += __shfl_xor(s, o, 64);
  if (lane == 0) sred[wid] = s;
  __syncthreads();
  s = sred[0] + sred[1] + sred[2] + sred[3];
  const float inv = 1.0f / s;

  unsigned short* prow = P + ro;
  for (int j = t; j < wlimit; j += 256)
    prow[j] = (j < valid) ? f2bf(__expf(srow[j] - m) * inv) : (unsigned short)0;
}

// fallback (non-split) softmax
__global__ __launch_bounds__(256) void softmax_causal(
    const float* __restrict__ S, unsigned short* __restrict__ P, int n) {
  __shared__ float srow[NC];
  __shared__ float sred[4];
  const int i = blockIdx.x;
  const int valid = i + 1;
  const int t = threadIdx.x;
  const int wid = t >> 6, lane = t & 63;
  const size_t ro = (size_t)i * n;
  for (int j = t; j < valid; j += 256) srow[j] = S[ro + j];
  __syncthreads();
  float m = -3.0e38f;
  for (int j = t; j < valid; j += 256) m = fmaxf(m, srow[j]);
#pragma unroll
  for (int o = 32; o > 0; o >>= 1) m = fmaxf(m, __shfl_xor(m, o, 64));
  if (lane == 0) sred[wid] = m;
  __syncthreads();
  m = fmaxf(fmaxf(sred[0], sred[1]), fmaxf(sred[2], sred[3]));
  __syncthreads();
  float s = 0.f;
  for (int j = t; j < valid; j += 256) s += __expf(srow[j] - m);
#pragma unroll
  for (int o = 32; o > 0; o >>= 1) s += __shfl_xor(s, o, 64);
  if (lane == 0) sred[wid] = s;
  __syncthreads();
  s = sred[0] + sred[1] + sred[2] + sred[3];
  const float inv = 1.0f / s;
  unsigned short* prow = P + ro;
  for (int j = t; j < n; j += 256)
    prow[j] = (j < valid) ? f2bf(__expf(srow[j] - m) * inv) : (unsigned short)0;
}

// PV reduce with causal slice skip
__global__ __launch_bounds__(256) void reduce_pv_causal(
    const float* __restrict__ part, unsigned short* __restrict__ out, size_t n,
    size_t stride) {
  const size_t i = ((size_t)blockIdx.x * 256 + threadIdx.x) * 4;
  if (i >= n) return;
  const int row = (int)(i >> 10);  // i / DM
  const int nsl = (row >> 9) + 1;  // 1..4 contributing slices
  float4 v = *reinterpret_cast<const float4*>(part + i);
  for (int s = 1; s < nsl; s++) {
    const float4 w = *reinterpret_cast<const float4*>(part + (size_t)s * stride + i);
    v.x += w.x; v.y += w.y; v.z += w.z; v.w += w.w;
  }
  u16x4_t o;
  o[0] = f2bf(v.x); o[1] = f2bf(v.y); o[2] = f2bf(v.z); o[3] = f2bf(v.w);
  *reinterpret_cast<u16x4_t*>(out + i) = o;
}

// x += b_down + sum4(down_part) + sum2(ov_part); xb = bf16(x); xT = xb^T
// (fallback split path)
__global__ __launch_bounds__(256) void residual_tiled(
    float* __restrict__ x, unsigned short* __restrict__ xb,
    unsigned short* __restrict__ xT, const float* __restrict__ dp,
    const float* __restrict__ op, const float* __restrict__ bd) {
  __shared__ unsigned short tile[32][33];
  const int tx = threadIdx.x;  // 0..7
  const int ty = threadIdx.y;  // 0..31
  const int col0 = blockIdx.x * 32;
  const int row0 = blockIdx.y * 32;
  const size_t n = (size_t)NC * DM;
  const int row = row0 + ty;
  const int col = col0 + tx * 4;
  const size_t idx = (size_t)row * DM + col;

  float4 v = *reinterpret_cast<const float4*>(x + idx);
  const float4 b = *reinterpret_cast<const float4*>(bd + col);
  v.x += b.x; v.y += b.y; v.z += b.z; v.w += b.w;
#pragma unroll
  for (int s = 0; s < 4; s++) {
    const float4 w = *reinterpret_cast<const float4*>(dp + (size_t)s * n + idx);
    v.x += w.x; v.y += w.y; v.z += w.z; v.w += w.w;
  }
#pragma unroll
  for (int s = 0; s < 2; s++) {
    const float4 w = *reinterpret_cast<const float4*>(op + (size_t)s * n + idx);
    v.x += w.x; v.y += w.y; v.z += w.z; v.w += w.w;
  }
  *reinterpret_cast<float4*>(x + idx) = v;
  u16x4_t o;
  o[0] = f2bf(v.x); o[1] = f2bf(v.y); o[2] = f2bf(v.z); o[3] = f2bf(v.w);
  *reinterpret_cast<u16x4_t*>(xb + idx) = o;
  tile[ty][tx * 4 + 0] = o[0];
  tile[ty][tx * 4 + 1] = o[1];
  tile[ty][tx * 4 + 2] = o[2];
  tile[ty][tx * 4 + 3] = o[3];
  __syncthreads();

  const int t = ty * 8 + tx;
  const int wc = t >> 5;
  const int wr = t & 31;
#pragma unroll
  for (int j = 0; j < 4; j++) {
    const int c = wc + j * 8;
    xT[(size_t)(col0 + c) * NC + row0 + wr] = tile[wr][c];
  }
}

// fallback residual
__global__ __launch_bounds__(256) void residual_kernel(
    float* __restrict__ x, const float* __restrict__ hd,
    const float* __restrict__ attn, unsigned short* __restrict__ xb, int n) {
  const int idx = blockIdx.x * 256 + threadIdx.x;
  if (idx < n) {
    const float v = x[idx] + hd[idx] + attn[idx];
    x[idx] = v;
    xb[idx] = f2bf(v);
  }
}

// ---------------------------------------------------------------------------
extern "C" void kernel_launch(void* const* d_in, const int* in_sizes, int n_in,
                              void* d_out, int out_size, void* d_ws,
                              size_t ws_size, hipStream_t stream) {
  const int* tokens = (const int*)d_in[0];
  const float* tok_emb = (const float*)d_in[1];
  const float* pos_emb = (const float*)d_in[2];
  const float* wqk = (const float*)d_in[3];
  const float* wov = (const float*)d_in[4];
  const float* w_up = (const float*)d_in[5];
  const float* b_up = (const float*)d_in[6];
  const float* w_down = (const float*)d_in[7];
  const float* b_down = (const float*)d_in[8];
  float* logits = (float*)d_out;

  uint8_t* base = (uint8_t*)d_ws;
  size_t used = 0;
  auto alloc = [&](size_t bytes) -> void* {
    const size_t ab = (bytes + 255) & ~(size_t)255;
    if (used + ab > ws_size) return (void*)0;
    void* r = base + used;
    used += ab;
    return r;
  };

  // mandatory
  float* x = (float*)alloc((size_t)NC * DM * 4);
  unsigned short* xb = (unsigned short*)alloc((size_t)NC * DM * 2);
  unsigned short* h1 = (unsigned short*)alloc((size_t)NC * DH * 2);
  unsigned short* qb = (unsigned short*)alloc((size_t)NC * DM * 2);
  unsigned short* Pb = (unsigned short*)alloc((size_t)NC * NC * 2);
  unsigned short* xT = (unsigned short*)alloc((size_t)NC * DM * 2);
  unsigned short* ab = (unsigned short*)alloc((size_t)NC * DM * 2);
  unsigned short* wqkT = (unsigned short*)alloc((size_t)NL * DM * DM * 2);
  unsigned short* wovT = (unsigned short*)alloc((size_t)NL * DM * DM * 2);
  float* hd = (float*)alloc((size_t)NC * DM * 4);
  float* attn = (float*)alloc((size_t)NC * DM * 4);
  float* scores = (float*)alloc((size_t)NC * NC * 4);
  // optional tiers
  float* dpart = (float*)alloc((size_t)4 * NC * DM * 4);   // 32 MB (4 slices)
  float* opart = (float*)alloc((size_t)2 * NC * DM * 4);   // 16 MB
  float* pool = (float*)alloc((size_t)2 * NC * NC * 4);    // 32 MB
  unsigned short* wupB = (unsigned short*)alloc((size_t)NL * DH * DM * 2);    // 64 MB
  unsigned short* wdownB = (unsigned short*)alloc((size_t)NL * DM * DH * 2);  // 64 MB
  unsigned short* tokB = (unsigned short*)alloc((size_t)DV * DM * 2);         // 62.5 MB

  const bool split_en = (dpart && opart && pool);
  const bool have_wbf = (wupB && wdownB);
  const bool have_tok = (tokB != 0);
  const bool fused_en = split_en && have_wbf;

  const dim3 tb(32, 8);
  if (fused_en) {
    // layer-0 wqk/wov only; layers 1..7 transposed in-loop (tail segments).
    transpose_cast_dual<<<dim3(DM / 32, DM / 32, 2), tb, 0, stream>>>(
        wqk, wqkT, wov, wovT, DM, DM, 1);
  } else {
    transpose_cast_dual<<<dim3(DM / 32, DM / 32, 2 * NL), tb, 0, stream>>>(
        wqk, wqkT, wov, wovT, DM, DM, NL);
    if (have_wbf && have_tok)
      cast3_f32_bf16<<<3 * 2048, 256, 0, stream>>>(
          w_up, wupB, (size_t)NL * DH * DM, w_down, wdownB, (size_t)NL * DM * DH,
          tok_emb, tokB, (size_t)DV * DM, 2048);
  }
  embed_kernel<<<NC, 256, 0, stream>>>(tokens, tok_emb, pos_emb, x, xb);
  transpose_u16<<<dim3(DM / 32, NC / 32), tb, 0, stream>>>(xb, xT, NC, DM);

  const size_t nMD = (size_t)NC * DM;
  const size_t tokQ = (size_t)DV * DM / (2 * NL);  // 2,048,000 (mult of 8)

  for (int l = 0; l < NL; l++) {
    if (fused_en) {
      // cast work for next layer's weights + this layer's tok_emb slice
      const bool nw = (l + 1 < NL);
      const float* u0s = nw ? w_up + (size_t)(l + 1) * DH * DM : nullptr;
      unsigned short* u0d = nw ? wupB + (size_t)(l + 1) * DH * DM : nullptr;
      const size_t u0n = nw ? (size_t)DH * DM : 0;
      const float* d0s = nw ? w_down + (size_t)(l + 1) * DM * DH : nullptr;
      unsigned short* d0d = nw ? wdownB + (size_t)(l + 1) * DM * DH : nullptr;
      const size_t d0n = nw ? (size_t)DM * DH : 0;
      const float* t0s = have_tok ? tok_emb + (size_t)l * 2 * tokQ : nullptr;
      unsigned short* t0d = have_tok ? tokB + (size_t)l * 2 * tokQ : nullptr;
      const float* t1s = have_tok ? tok_emb + (size_t)l * 2 * tokQ + tokQ : nullptr;
      unsigned short* t1d = have_tok ? tokB + (size_t)l * 2 * tokQ + tokQ : nullptr;
      const size_t tn = have_tok ? tokQ : 0;
      // next-layer wqk/wov transpose (tail segment of fused_up_q)
      const float* tr0s = nw ? wqk + (size_t)(l + 1) * DM * DM : nullptr;
      unsigned short* tr0d = nw ? wqkT + (size_t)(l + 1) * DM * DM : nullptr;
      const float* tr1s = nw ? wov + (size_t)(l + 1) * DM * DM : nullptr;
      unsigned short* tr1d = nw ? wovT + (size_t)(l + 1) * DM * DM : nullptr;

      // ---- up + q(full) + cast + transpose in one launch ----
      if (l == 0)
        fused_up_q<true><<<2048, 256, 0, stream>>>(
            xb, w_up, b_up, h1, wqkT, qb, u0s, u0d, u0n, t0s, t0d, tn,
            tr0s, tr0d, tr1s, tr1d);
      else
        fused_up_q<false><<<2048, 256, 0, stream>>>(
            xb, wupB + (size_t)l * DH * DM, b_up + (size_t)l * DH, h1,
            wqkT + (size_t)l * DM * DM, qb, u0s, u0d, u0n, t0s, t0d, tn,
            tr0s, tr0d, tr1s, tr1d);
      // ---- down(split4) + scores(split2) + cast in one launch ----
      if (l == 0)
        fused_down_sc<true><<<2560, 256, 0, stream>>>(
            h1, w_down, dpart, qb, xb, pool, d0s, d0d, d0n, t1s, t1d, tn);
      else
        fused_down_sc<false><<<2560, 256, 0, stream>>>(
            h1, wdownB + (size_t)l * DM * DH, dpart, qb, xb, pool, d0s, d0d,
            d0n, t1s, t1d, tn);
      // ---- softmax over summed score slices ----
      softmax_split2<<<NC, 256, 0, stream>>>(pool, pool + (size_t)NC * NC, Pb, NC);
      // ---- attn partials a = P @ x  [2048,1024], K=2048 split 4 causal ----
      gemm_nt<64, false, true, false, true, false, false, false>
          <<<dim3(DM / 64, NC / 128, 4), 256, 0, stream>>>(
              Pb, xT, nullptr, pool, NC, DM, NC, NC / 4);
      reduce_pv_causal<<<(nMD / 4 + 255) / 256, 256, 0, stream>>>(pool, ab, nMD, nMD);
      // ---- ov + residual fused: x,xb,xT updated in one launch ----
      gemm_ov_res<<<dim3(DM / 64, NC / 128), 256, 0, stream>>>(
          ab, wovT + (size_t)l * DM * DM, x, xb, xT, dpart,
          b_down + (size_t)l * DM);
    } else {
      gemm_nt<64, true, false, false, false, true, true, true>
          <<<dim3(DH / 64, NC / 128), 256, 0, stream>>>(
              xb, w_up + (size_t)l * DH * DM, b_up + (size_t)l * DH, h1, NC, DH, DM, DM);
      gemm_nt<64, true, false, false, false, true, false, false>
          <<<dim3(DM / 64, NC / 128), 256, 0, stream>>>(
              h1, w_down + (size_t)l * DM * DH, b_down + (size_t)l * DM, hd, NC, DM, DH, DH);
      gemm_nt<64, false, false, false, false, false, false, true>
          <<<dim3(DM / 64, NC / 128), 256, 0, stream>>>(
              xb, wqkT + (size_t)l * DM * DM, nullptr, qb, NC, DM, DM, DM);

      if (split_en) {
        gemm_nt<64, false, true, true, false, false, false, false>
            <<<dim3(NC / 64, NC / 128, 2), 256, 0, stream>>>(
                qb, xb, nullptr, pool, NC, NC, DM, DM / 2);
        softmax_split2<<<NC, 256, 0, stream>>>(pool, pool + (size_t)NC * NC, Pb, NC);
        gemm_nt<64, false, true, false, true, false, false, false>
            <<<dim3(DM / 64, NC / 128, 4), 256, 0, stream>>>(
                Pb, xT, nullptr, pool, NC, DM, NC, NC / 4);
        reduce_pv_causal<<<(nMD / 4 + 255) / 256, 256, 0, stream>>>(pool, ab, nMD, nMD);
        gemm_nt<64, false, true, false, false, false, false, false>
            <<<dim3(DM / 64, NC / 128, 2), 256, 0, stream>>>(
                ab, wovT + (size_t)l * DM * DM, nullptr, opart, NC, DM, DM, DM / 2);
        residual_tiled<<<dim3(DM / 32, NC / 32), dim3(8, 32), 0, stream>>>(
            x, xb, xT, dpart, opart, b_down + (size_t)l * DM);
      } else {
        gemm_nt<64, false, false, true, false, false, false, false>
            <<<dim3(NC / 64, NC / 128), 256, 0, stream>>>(
                qb, xb, nullptr, scores, NC, NC, DM, DM);
        softmax_causal<<<NC, 256, 0, stream>>>(scores, Pb, NC);
        transpose_u16<<<dim3(DM / 32, NC / 32), tb, 0, stream>>>(xb, xT, NC, DM);
        gemm_nt<64, false, false, false, true, false, false, true>
            <<<dim3(DM / 64, NC / 128), 256, 0, stream>>>(
                Pb, xT, nullptr, ab, NC, DM, NC, NC);
        gemm_nt<64, false, false, false, false, false, false, false>
            <<<dim3(DM / 64, NC / 128), 256, 0, stream>>>(
                ab, wovT + (size_t)l * DM * DM, nullptr, attn, NC, DM, DM, DM);
        residual_kernel<<<(int)(nMD / 256), 256, 0, stream>>>(x, hd, attn, xb, (int)nMD);
      }
    }
  }

  // ---- logits = x @ tok_emb^T  [2048,32000] fp32, BN=64 (proven ~204us) ----
  if (have_tok && fused_en)
    gemm_nt<64, false, false, false, false, false, false, false>
        <<<dim3(DV / 64, NC / 128), 256, 0, stream>>>(
            xb, tokB, nullptr, logits, NC, DV, DM, DM);
  else if (have_tok && have_wbf)
    gemm_nt<64, false, false, false, false, false, false, false>
        <<<dim3(DV / 64, NC / 128), 256, 0, stream>>>(
            xb, tokB, nullptr, logits, NC, DV, DM, DM);
  else
    gemm_nt<64, true, false, false, false, false, false, false>
        <<<dim3(DV / 64, NC / 128), 256, 0, stream>>>(
            xb, tok_emb, nullptr, logits, NC, DV, DM, DM);
}

// Round 10
// 1252.484 us; speedup vs baseline: 1.0025x; 1.0025x over previous
//
#include <hip/hip_runtime.h>
#include <hip/hip_bf16.h>
#include <stdint.h>

#define DM 1024
#define DH 4096
#define DV 32000
#define NC 2048
#define NL 8

typedef float f32x4_t __attribute__((ext_vector_type(4)));
typedef __bf16 bf16x8_t __attribute__((ext_vector_type(8)));
typedef unsigned short u16x4_t __attribute__((ext_vector_type(4)));
typedef unsigned short u16x8_t __attribute__((ext_vector_type(8)));

typedef __attribute__((address_space(1))) void as1_void;
typedef __attribute__((address_space(3))) void as3_void;

__device__ __forceinline__ unsigned short f2bf(float f) {
  unsigned int u = __builtin_bit_cast(unsigned int, f);
  u += 0x7fffu + ((u >> 16) & 1u);  // round-to-nearest-even
  return (unsigned short)(u >> 16);
}

__device__ __forceinline__ void gload_lds16(const void* g, void* l) {
  __builtin_amdgcn_global_load_lds((as1_void*)(void*)g, (as3_void*)l, 16, 0, 0);
}

// grid-stride f32->bf16 cast tail segment: cidx in [0,512), 256 threads.
// Covers [0,n) in 8-elem chunks; n must be a multiple of 8.
__device__ __forceinline__ void cast_tail8(const float* __restrict__ src,
                                           unsigned short* __restrict__ dst,
                                           size_t n, int cidx, int tid) {
  for (size_t i = (size_t)cidx * 2048 + (size_t)tid * 8; i < n;
       i += (size_t)512 * 2048) {
    const float4 a = *reinterpret_cast<const float4*>(src + i);
    const float4 b = *reinterpret_cast<const float4*>(src + i + 4);
    u16x8_t v;
    v[0] = f2bf(a.x); v[1] = f2bf(a.y); v[2] = f2bf(a.z); v[3] = f2bf(a.w);
    v[4] = f2bf(b.x); v[5] = f2bf(b.y); v[6] = f2bf(b.z); v[7] = f2bf(b.w);
    *reinterpret_cast<u16x8_t*>(dst + i) = v;
  }
}

// ---------------------------------------------------------------------------
// NT bf16 MFMA GEMM body: C[M][N] = A[M][K] * Bt[N][K]^T, one 128xBN tile.
// BM=128, BN=64, BK=64, 256 threads (4 waves 2x2), wave tile 64x32.
// Chunk swizzle ^(r&7): measured 0 bank conflicts. Caller owns decode + LDS.
// NOTE r1/r2: BN=128 via 4-wave (152 regs, occupancy cliff) and via 8-wave
// 512thr both failed to beat this: structure is latency-bound on the
// vmcnt(0)+barrier drain, not tile-shape-bound. Keep BN=64.
// NOTE r4: OV reassociation P@(x@wov) FAILED absmax (0.176 > 0.164) —
// moving the bf16 quantization onto v=x@wov amplifies through P. Do not.
// NOTE r7: K-chain REASSOCIATION (down split 4->2, scores split2->fullK)
// FAILED absmax (0.197 > 0.164) despite no structural bug — bf16 rounding
// flips at f2bf boundaries compound through 8 layers. Only BIT-IDENTICAL
// transforms are safe; keep down split-4 + scores split-2 as verified.
// NOTE r8: skipping layer-7 x/xT stores (analysis: bit-identical) passed the
// first check but DIVERGED after graph-replay timing (2.5 absmax). No
// store-skip edits on persistent buffers without on-box debugging.
// ---------------------------------------------------------------------------
template <int BNT, bool B_FP32, bool SPLIT, bool CAUSAL, bool CAUSAL_K,
          bool HAS_BIAS, bool RELU, bool OUT_BF16>
__device__ __forceinline__ void gemm_body(
    unsigned short* As, unsigned short* Bs, const unsigned short* __restrict__ A,
    const void* __restrict__ Bt, const float* __restrict__ bias,
    void* __restrict__ Cout, int M, int N, int lda, int Ks, int bx, int by,
    int koff, int zslice) {
  constexpr int BK = 64;
  constexpr int BN = BNT;
  constexpr int CPTA = 4;
  constexpr int CPTB = (BN * BK) / 2048;
  constexpr int NF = BN / 32;
  const int t = threadIdx.x;
  const int lane = t & 63;
  const int wid = t >> 6;
  const int wr = wid >> 1, wc = wid & 1;
  const int row0 = by * 128;
  const int col0 = bx * BN;

  if constexpr (CAUSAL) {
    if (col0 > row0 + 127) return;  // fully-masked tile (uniform exit)
  }

  int Kend = Ks;
  if constexpr (CAUSAL_K) {
    const int need = row0 + 128 - koff;  // need k < row0+128 (P lower-tri)
    Kend = need <= 0 ? 0 : (need >= Ks ? Ks : ((need + BK - 1) & ~(BK - 1)));
    if constexpr (SPLIT) {
      if (Kend <= 0) return;  // partials are exact zeros; consumer skips them
    }
  }

  f32x4_t acc[4][NF];
#pragma unroll
  for (int m = 0; m < 4; m++)
#pragma unroll
    for (int n = 0; n < NF; n++) acc[m][n] = (f32x4_t){0.f, 0.f, 0.f, 0.f};

  for (int kt = 0; kt < Kend; kt += BK) {
    __syncthreads();
    // ---- stage A: 128x64 bf16, 4 chunks per thread ----
#pragma unroll
    for (int i = 0; i < CPTA; i++) {
      const int c = i * 256 + t;
      const int r = c >> 3;
      const int ko = ((c & 7) ^ (r & 7)) * 8;  // pre-swizzled source chunk
      const unsigned short* g = A + (size_t)(row0 + r) * lda + koff + kt + ko;
      unsigned short* l = &As[(size_t)(i * 256 + wid * 64) * 8];  // wave-uniform
      gload_lds16(g, l);
    }
    // ---- stage B: BNx64 bf16 ----
    if constexpr (B_FP32) {
      const float* Bf = (const float*)Bt;
#pragma unroll
      for (int i = 0; i < CPTB; i++) {
        const int c = i * 256 + t;
        const int r = c >> 3;
        const int ko = ((c & 7) ^ (r & 7)) * 8;
        const float* g = Bf + (size_t)(col0 + r) * lda + koff + kt + ko;
        const float4 f0 = *reinterpret_cast<const float4*>(g);
        const float4 f1 = *reinterpret_cast<const float4*>(g + 4);
        u16x8_t v;
        v[0] = f2bf(f0.x); v[1] = f2bf(f0.y); v[2] = f2bf(f0.z); v[3] = f2bf(f0.w);
        v[4] = f2bf(f1.x); v[5] = f2bf(f1.y); v[6] = f2bf(f1.z); v[7] = f2bf(f1.w);
        *reinterpret_cast<u16x8_t*>(&Bs[(size_t)c * 8]) = v;
      }
    } else {
      const unsigned short* Bu = (const unsigned short*)Bt;
#pragma unroll
      for (int i = 0; i < CPTB; i++) {
        const int c = i * 256 + t;
        const int r = c >> 3;
        const int ko = ((c & 7) ^ (r & 7)) * 8;
        const unsigned short* g = Bu + (size_t)(col0 + r) * lda + koff + kt + ko;
        unsigned short* l = &Bs[(size_t)(i * 256 + wid * 64) * 8];
        gload_lds16(g, l);
      }
    }
    __syncthreads();

    // ---- fragments + MFMA (2 k-slices of 32, ascending k) ----
#pragma unroll
    for (int kk = 0; kk < 2; kk++) {
      bf16x8_t av[4], bv[NF];
#pragma unroll
      for (int m = 0; m < 4; m++) {
        const int arow = wr * 64 + m * 16 + (lane & 15);
        const int akc = (kk * 4 + (lane >> 4)) ^ (arow & 7);
        av[m] = __builtin_bit_cast(
            bf16x8_t, *reinterpret_cast<const u16x8_t*>(&As[arow * BK + akc * 8]));
      }
#pragma unroll
      for (int n = 0; n < NF; n++) {
        const int brow = wc * (BN / 2) + n * 16 + (lane & 15);
        const int bkc = (kk * 4 + (lane >> 4)) ^ (brow & 7);
        bv[n] = __builtin_bit_cast(
            bf16x8_t, *reinterpret_cast<const u16x8_t*>(&Bs[brow * BK + bkc * 8]));
      }
#pragma unroll
      for (int m = 0; m < 4; m++)
#pragma unroll
        for (int n = 0; n < NF; n++)
          acc[m][n] = __builtin_amdgcn_mfma_f32_16x16x32_bf16(av[m], bv[n],
                                                              acc[m][n], 0, 0, 0);
    }
  }

  // ---- epilogue: C/D layout col=lane&15, row=(lane>>4)*4+j ----
#pragma unroll
  for (int m = 0; m < 4; m++) {
    const int rbase = row0 + wr * 64 + m * 16 + (lane >> 4) * 4;
#pragma unroll
    for (int n = 0; n < NF; n++) {
      const int col = col0 + wc * (BN / 2) + n * 16 + (lane & 15);
      if constexpr (SPLIT) {
        float* out = (float*)Cout + (size_t)zslice * M * N;
#pragma unroll
        for (int j = 0; j < 4; j++)
          out[(size_t)(rbase + j) * N + col] = acc[m][n][j];
      } else {
        float bval = 0.0f;
        if constexpr (HAS_BIAS) bval = bias[col];
#pragma unroll
        for (int j = 0; j < 4; j++) {
          float v = acc[m][n][j];
          if constexpr (HAS_BIAS) v += bval;
          if constexpr (RELU) v = fmaxf(v, 0.0f);
          const size_t idx = (size_t)(rbase + j) * N + col;
          if constexpr (OUT_BF16)
            ((unsigned short*)Cout)[idx] = f2bf(v);
          else
            __builtin_nontemporal_store(v, (float*)Cout + idx);
        }
      }
    }
  }
}

// 4x4 super-tile decode on a linear id over (GX x GY) tiles, column-major
// supers (requires GX%4==0 && GY%4==0).
__device__ __forceinline__ void super_decode(int idx, int gy, int& bx, int& by) {
  const int s = idx >> 4;
  const int u = idx & 15;
  const int sgy = gy >> 2;
  const int sx = s / sgy;
  const int sy = s - sx * sgy;
  bx = sx * 4 + (u & 3);
  by = sy * 4 + (u >> 2);
}

// ---------------------------------------------------------------------------
// standalone GEMM wrapper (decode: m204 XCD chunk + 4x4 super-tile)
// ---------------------------------------------------------------------------
template <int BNT, bool B_FP32, bool SPLIT, bool CAUSAL, bool CAUSAL_K,
          bool HAS_BIAS, bool RELU, bool OUT_BF16>
__global__ __launch_bounds__(256) void gemm_nt(
    const unsigned short* __restrict__ A, const void* __restrict__ Bt,
    const float* __restrict__ bias, void* __restrict__ Cout, int M, int N,
    int lda, int Ks) {
  __shared__ __attribute__((aligned(16))) unsigned short As[128 * 64];
  __shared__ __attribute__((aligned(16))) unsigned short Bs[BNT * 64];
  const int gx = gridDim.x, gy = gridDim.y;
  const int nwg = gx * gy;
  const int orig = blockIdx.y * gx + blockIdx.x;
  const int qq = nwg >> 3, rr = nwg & 7;
  const int xc = orig & 7, ii = orig >> 3;
  const int wgid = (xc < rr ? xc * (qq + 1) : rr * (qq + 1) + (xc - rr) * qq) + ii;
  int bx, by;
  super_decode(wgid, gy, bx, by);
  gemm_body<BNT, B_FP32, SPLIT, CAUSAL, CAUSAL_K, HAS_BIAS, RELU, OUT_BF16>(
      As, Bs, A, Bt, bias, Cout, M, N, lda, Ks, bx, by,
      SPLIT ? blockIdx.z * Ks : 0, blockIdx.z);
}

// ---------------------------------------------------------------------------
// ov GEMM + fused residual: C = ab @ wovT^T (full K=DM), then
// v = C + x + b_down + sum4(dpart); writes x (f32), xb (bf16), xT (bf16^T).
// Grid 16x16 (tiles of 128x64). xT store: acc j-index walks rows at fixed
// col -> 4 consecutive u16 at xT[col*NC + rbase], one u16x4 store.
// (r8: do NOT skip the layer-7 x/xT stores — replay divergence.)
// ---------------------------------------------------------------------------
__global__ __launch_bounds__(256) void gemm_ov_res(
    const unsigned short* __restrict__ A, const unsigned short* __restrict__ Bt,
    float* __restrict__ x, unsigned short* __restrict__ xb,
    unsigned short* __restrict__ xT, const float* __restrict__ dp,
    const float* __restrict__ bd) {
  __shared__ __attribute__((aligned(16))) unsigned short As[128 * 64];
  __shared__ __attribute__((aligned(16))) unsigned short Bs[64 * 64];
  const int gx = gridDim.x, gy = gridDim.y;
  const int nwg = gx * gy;
  const int orig = blockIdx.y * gx + blockIdx.x;
  const int qq = nwg >> 3, rr = nwg & 7;
  const int xc = orig & 7, ii = orig >> 3;
  const int wgid = (xc < rr ? xc * (qq + 1) : rr * (qq + 1) + (xc - rr) * qq) + ii;
  int bx, by;
  super_decode(wgid, gy, bx, by);

  const int t = threadIdx.x;
  const int lane = t & 63;
  const int wid = t >> 6;
  const int wr = wid >> 1, wc = wid & 1;
  const int row0 = by * 128;
  const int col0 = bx * 64;

  f32x4_t acc[4][2];
#pragma unroll
  for (int m = 0; m < 4; m++)
#pragma unroll
    for (int n = 0; n < 2; n++) acc[m][n] = (f32x4_t){0.f, 0.f, 0.f, 0.f};

  for (int kt = 0; kt < DM; kt += 64) {
    __syncthreads();
#pragma unroll
    for (int i = 0; i < 4; i++) {
      const int c = i * 256 + t;
      const int r = c >> 3;
      const int ko = ((c & 7) ^ (r & 7)) * 8;
      const unsigned short* g = A + (size_t)(row0 + r) * DM + kt + ko;
      unsigned short* l = &As[(size_t)(i * 256 + wid * 64) * 8];
      gload_lds16(g, l);
    }
#pragma unroll
    for (int i = 0; i < 2; i++) {
      const int c = i * 256 + t;
      const int r = c >> 3;
      const int ko = ((c & 7) ^ (r & 7)) * 8;
      const unsigned short* g = Bt + (size_t)(col0 + r) * DM + kt + ko;
      unsigned short* l = &Bs[(size_t)(i * 256 + wid * 64) * 8];
      gload_lds16(g, l);
    }
    __syncthreads();

#pragma unroll
    for (int kk = 0; kk < 2; kk++) {
      bf16x8_t av[4], bv[2];
#pragma unroll
      for (int m = 0; m < 4; m++) {
        const int arow = wr * 64 + m * 16 + (lane & 15);
        const int akc = (kk * 4 + (lane >> 4)) ^ (arow & 7);
        av[m] = __builtin_bit_cast(
            bf16x8_t, *reinterpret_cast<const u16x8_t*>(&As[arow * 64 + akc * 8]));
      }
#pragma unroll
      for (int n = 0; n < 2; n++) {
        const int brow = wc * 32 + n * 16 + (lane & 15);
        const int bkc = (kk * 4 + (lane >> 4)) ^ (brow & 7);
        bv[n] = __builtin_bit_cast(
            bf16x8_t, *reinterpret_cast<const u16x8_t*>(&Bs[brow * 64 + bkc * 8]));
      }
#pragma unroll
      for (int m = 0; m < 4; m++)
#pragma unroll
        for (int n = 0; n < 2; n++)
          acc[m][n] = __builtin_amdgcn_mfma_f32_16x16x32_bf16(av[m], bv[n],
                                                              acc[m][n], 0, 0, 0);
    }
  }

  const size_t nMD = (size_t)NC * DM;
#pragma unroll
  for (int m = 0; m < 4; m++) {
    const int rbase = row0 + wr * 64 + m * 16 + (lane >> 4) * 4;
#pragma unroll
    for (int n = 0; n < 2; n++) {
      const int col = col0 + wc * 32 + n * 16 + (lane & 15);
      const float bval = bd[col];
      u16x4_t ot;
#pragma unroll
      for (int j = 0; j < 4; j++) {
        const size_t idx = (size_t)(rbase + j) * DM + col;
        float v = acc[m][n][j] + x[idx] + bval;
#pragma unroll
        for (int s = 0; s < 4; s++) v += dp[(size_t)s * nMD + idx];
        x[idx] = v;
        const unsigned short o = f2bf(v);
        xb[idx] = o;
        ot[j] = o;
      }
      *reinterpret_cast<u16x4_t*>(&xT[(size_t)col * NC + rbase]) = ot;
    }
  }
}

// ---------------------------------------------------------------------------
// fused embed + layer-0 wqk/wov transpose: 2304 blocks.
// blocks [0,2048): embed row (exact embed_kernel code).
// blocks [2048,2304): layer-0 weight transpose, 8 tiles/block over 2048
// tiles (2 matrices x 1024) — exact copy of the verified fused_up_q tail.
// Disjoint read/write sets; outputs bit-identical to the old prologue.
// ---------------------------------------------------------------------------
__global__ __launch_bounds__(256) void embed_tr(
    const int* __restrict__ tokens, const float* __restrict__ tok_emb,
    const float* __restrict__ pos_emb, float* __restrict__ x,
    unsigned short* __restrict__ xb, const float* __restrict__ wqk0,
    unsigned short* __restrict__ wqkT0, const float* __restrict__ wov0,
    unsigned short* __restrict__ wovT0) {
  __shared__ float tf[32 * 33];
  const int b = blockIdx.x;
  if (b < NC) {
    const int tok = tokens[b];
    const float* te = tok_emb + (size_t)tok * DM;
    const float* pe = pos_emb + (size_t)b * DM;
    float* xr = x + (size_t)b * DM;
    unsigned short* xbr = xb + (size_t)b * DM;
    const int j = threadIdx.x * 4;
    const float4 a = *reinterpret_cast<const float4*>(te + j);
    const float4 p = *reinterpret_cast<const float4*>(pe + j);
    float4 v;
    v.x = a.x + p.x; v.y = a.y + p.y; v.z = a.z + p.z; v.w = a.w + p.w;
    *reinterpret_cast<float4*>(xr + j) = v;
    u16x4_t o;
    o[0] = f2bf(v.x); o[1] = f2bf(v.y); o[2] = f2bf(v.z); o[3] = f2bf(v.w);
    *reinterpret_cast<u16x4_t*>(xbr + j) = o;
  } else {
    const int tb = b - NC;                // [0,256)
    const int tx = threadIdx.x & 31;
    const int ty = threadIdx.x >> 5;      // 0..7
#pragma unroll 1
    for (int jj = 0; jj < 8; jj++) {
      const int j = tb * 8 + jj;          // [0,2048): 2 matrices x 1024 tiles
      const float* src = (j < 1024) ? wqk0 : wov0;
      unsigned short* dst = (j < 1024) ? wqkT0 : wovT0;
      const int tile = j & 1023;
      const int tX = tile & 31, tY = tile >> 5;
      __syncthreads();
#pragma unroll
      for (int i = 0; i < 4; i++) {
        const int r = ty + i * 8;
        tf[r * 33 + tx] = src[(size_t)(tY * 32 + r) * DM + tX * 32 + tx];
      }
      __syncthreads();
#pragma unroll
      for (int i = 0; i < 4; i++) {
        const int r = ty + i * 8;
        dst[(size_t)(tX * 32 + r) * DM + tY * 32 + tx] = f2bf(tf[tx * 33 + r]);
      }
    }
  }
}

// ---------------------------------------------------------------------------
// fused up + q + weight-cast + next-layer wqk/wov transpose (+ layer-0 xT):
// grid 2048 (l>0) or 2304 (l==0). Chunks per XCD: 128 up + 32 q + 64 cast +
// 32 w-transpose [+ 32 xT-transpose, l==0 only].
// up: h1 = relu(xb @ wup^T + b_up)  [2048,4096]; WUP32: layer-0 reads w_up
//     fp32 directly (in-stage f2bf = bit-identical to pre-cast).
// q:  qb = bf16(xb @ wqkT_l)        [2048,1024], K=1024 full.
// cast: streams next-layer w_up + tok slice under the GEMMs' BW slack.
// transpose: wqkT/wovT for layer l+1; consumers in later launches.
// xT tail (l==0): xb -> xT u16 transpose (first consumer: PV, 3 launches
//     later). Replaces the standalone prologue transpose_u16.
// ---------------------------------------------------------------------------
template <bool WUP32>
__global__ __launch_bounds__(256) void fused_up_q(
    const unsigned short* __restrict__ xb, const void* __restrict__ wup,
    const float* __restrict__ bup, unsigned short* __restrict__ h1,
    const unsigned short* __restrict__ wqkT, unsigned short* __restrict__ qb,
    const float* __restrict__ c0s, unsigned short* __restrict__ c0d, size_t c0n,
    const float* __restrict__ c1s, unsigned short* __restrict__ c1d, size_t c1n,
    const float* __restrict__ tr0s, unsigned short* __restrict__ tr0d,
    const float* __restrict__ tr1s, unsigned short* __restrict__ tr1d,
    unsigned short* __restrict__ xTd) {
  __shared__ __attribute__((aligned(16))) unsigned short As[128 * 64];
  __shared__ __attribute__((aligned(16))) unsigned short Bs[64 * 64];
  const int orig = blockIdx.x;          // nwg = 2048 or 2304, %8 == 0
  const int xc = orig & 7, ii = orig >> 3;  // chunk = xc, local ii
  int bx, by;
  if (ii < 128) {
    const int idx = xc * 128 + ii;      // [0,1024) bijective
    super_decode(idx, 16, bx, by);      // gy=16 (grid 64x16)
    gemm_body<64, WUP32, false, false, false, true, true, true>(
        As, Bs, xb, wup, bup, h1, NC, DH, DM, DM, bx, by, 0, 0);
  } else if (ii < 160) {
    const int idx = xc * 32 + (ii - 128);  // [0,256) bijective
    super_decode(idx, 16, bx, by);         // gy=16 (grid 16x16)
    gemm_body<64, false, false, false, false, false, false, true>(
        As, Bs, xb, wqkT, nullptr, qb, NC, DM, DM, DM, bx, by, 0, 0);
  } else if (ii < 224) {
    const int cidx = xc * 64 + (ii - 160);  // [0,512) bijective
    cast_tail8(c0s, c0d, c0n, cidx, threadIdx.x);
    cast_tail8(c1s, c1d, c1n, cidx, threadIdx.x);
  } else if (ii < 256) {
    if (tr0s == nullptr) return;
    float* tf = (float*)As;               // 32x33 f32 tile (4224 B, fits 16K)
    const int tb = xc * 32 + (ii - 224);  // [0,256) bijective
    const int tx = threadIdx.x & 31;
    const int ty = threadIdx.x >> 5;      // 0..7
#pragma unroll 1
    for (int jj = 0; jj < 8; jj++) {
      const int j = tb * 8 + jj;          // [0,2048): 2 matrices x 1024 tiles
      const float* src = (j < 1024) ? tr0s : tr1s;
      unsigned short* dst = (j < 1024) ? tr0d : tr1d;
      const int tile = j & 1023;
      const int tX = tile & 31, tY = tile >> 5;
      __syncthreads();
#pragma unroll
      for (int i = 0; i < 4; i++) {
        const int r = ty + i * 8;
        tf[r * 33 + tx] = src[(size_t)(tY * 32 + r) * DM + tX * 32 + tx];
      }
      __syncthreads();
#pragma unroll
      for (int i = 0; i < 4; i++) {
        const int r = ty + i * 8;
        dst[(size_t)(tX * 32 + r) * DM + tY * 32 + tx] = f2bf(tf[tx * 33 + r]);
      }
    }
  } else {
    // xT = xb^T u16 transpose tail (only scheduled when grid == 2304, l==0)
    unsigned short* tu = (unsigned short*)As;  // [32][33] u16 tile
    const int tb = xc * 32 + (ii - 256);  // [0,256) bijective
    const int tx = threadIdx.x & 31;
    const int ty = threadIdx.x >> 5;      // 0..7
#pragma unroll 1
    for (int jj = 0; jj < 8; jj++) {
      const int j = tb * 8 + jj;          // [0,2048) tiles of [NC][DM]
      const int tX = j & 31, tY = j >> 5; // tX over DM/32, tY over NC/32
      __syncthreads();
#pragma unroll
      for (int i = 0; i < 4; i++) {
        const int r = ty + i * 8;
        tu[r * 33 + tx] = xb[(size_t)(tY * 32 + r) * DM + tX * 32 + tx];
      }
      __syncthreads();
#pragma unroll
      for (int i = 0; i < 4; i++) {
        const int r = ty + i * 8;
        xTd[(size_t)(tX * 32 + r) * NC + tY * 32 + tx] = tu[tx * 33 + r];
      }
    }
  }
}

// ---------------------------------------------------------------------------
// fused down + scores + weight-cast: 2560 blocks, 320/XCD =
//   128 down-gemm + 128 scores-gemm + 64 cast.
// down:   dpart[z] = h1 @ wdown-slice [2048,1024] split 4; WDN32: layer-0
//         reads w_down fp32 directly (bit-identical).
// scores: spool[z] = qb @ xb^T-slice  [2048,2048] split 2, causal tile-skip.
// (r7 lesson: do NOT change these split factors — reassociation fails absmax.)
// ---------------------------------------------------------------------------
template <bool WDN32>
__global__ __launch_bounds__(256) void fused_down_sc(
    const unsigned short* __restrict__ h1, const void* __restrict__ wdown,
    float* __restrict__ dpart, const unsigned short* __restrict__ qb,
    const unsigned short* __restrict__ xbv, float* __restrict__ spool,
    const float* __restrict__ c0s, unsigned short* __restrict__ c0d, size_t c0n,
    const float* __restrict__ c1s, unsigned short* __restrict__ c1d, size_t c1n) {
  __shared__ __attribute__((aligned(16))) unsigned short As[128 * 64];
  __shared__ __attribute__((aligned(16))) unsigned short Bs[64 * 64];
  const int orig = blockIdx.x;          // nwg = 2560, %8 == 0
  const int xc = orig & 7, ii = orig >> 3;  // chunk = xc, local ii in [0,320)
  if (ii < 128) {
    const int idx = xc * 128 + ii;      // [0,1024)
    const int z = idx >> 8;
    int bx, by;
    super_decode(idx & 255, 16, bx, by);
    gemm_body<64, WDN32, true, false, false, false, false, false>(
        As, Bs, h1, wdown, nullptr, dpart, NC, DM, DH, DH / 4, bx, by,
        z * (DH / 4), z);
  } else if (ii < 256) {
    const int idx = xc * 128 + (ii - 128);  // [0,1024)
    const int z = idx >> 9;
    int bx, by;
    super_decode(idx & 511, 16, bx, by);    // gy=16 (grid 32x16 per z)
    gemm_body<64, false, true, true, false, false, false, false>(
        As, Bs, qb, xbv, nullptr, spool, NC, NC, DM, DM / 2, bx, by,
        z * (DM / 2), z);
  } else {
    const int cidx = xc * 64 + (ii - 256);  // [0,512) bijective
    cast_tail8(c0s, c0d, c0n, cidx, threadIdx.x);
    cast_tail8(c1s, c1d, c1n, cidx, threadIdx.x);
  }
}

// ---------------------------------------------------------------------------
// three independent f32->bf16 casts in one launch (fallback path only)
__global__ __launch_bounds__(256) void cast3_f32_bf16(
    const float* __restrict__ in0, unsigned short* __restrict__ out0, size_t n0,
    const float* __restrict__ in1, unsigned short* __restrict__ out1, size_t n1,
    const float* __restrict__ in2, unsigned short* __restrict__ out2, size_t n2,
    int gper) {
  const int seg = blockIdx.x / gper;
  const int lb = blockIdx.x - seg * gper;
  const float* in = seg == 0 ? in0 : (seg == 1 ? in1 : in2);
  unsigned short* out = seg == 0 ? out0 : (seg == 1 ? out1 : out2);
  const size_t n = seg == 0 ? n0 : (seg == 1 ? n1 : n2);
  const size_t stride = (size_t)gper * 256 * 8;
  for (size_t i = ((size_t)lb * 256 + threadIdx.x) * 8; i < n; i += stride) {
    const float4 a = *reinterpret_cast<const float4*>(in + i);
    const float4 b = *reinterpret_cast<const float4*>(in + i + 4);
    u16x8_t v;
    v[0] = f2bf(a.x); v[1] = f2bf(a.y); v[2] = f2bf(a.z); v[3] = f2bf(a.w);
    v[4] = f2bf(b.x); v[5] = f2bf(b.y); v[6] = f2bf(b.z); v[7] = f2bf(b.w);
    *reinterpret_cast<u16x8_t*>(out + i) = v;
  }
}

// vectorized embed (fallback path only)
__global__ __launch_bounds__(256) void embed_kernel(
    const int* __restrict__ tokens, const float* __restrict__ tok_emb,
    const float* __restrict__ pos_emb, float* __restrict__ x,
    unsigned short* __restrict__ xb) {
  const int i = blockIdx.x;
  const int tok = tokens[i];
  const float* te = tok_emb + (size_t)tok * DM;
  const float* pe = pos_emb + (size_t)i * DM;
  float* xr = x + (size_t)i * DM;
  unsigned short* xbr = xb + (size_t)i * DM;
  const int j = threadIdx.x * 4;
  const float4 a = *reinterpret_cast<const float4*>(te + j);
  const float4 b = *reinterpret_cast<const float4*>(pe + j);
  float4 v;
  v.x = a.x + b.x; v.y = a.y + b.y; v.z = a.z + b.z; v.w = a.w + b.w;
  *reinterpret_cast<float4*>(xr + j) = v;
  u16x4_t o;
  o[0] = f2bf(v.x); o[1] = f2bf(v.y); o[2] = f2bf(v.z); o[3] = f2bf(v.w);
  *reinterpret_cast<u16x4_t*>(xbr + j) = o;
}

// fp32 [z][R][C] -> bf16 [z][C][R]; two tensors in one launch (fallback)
__global__ void transpose_cast_dual(const float* __restrict__ in0,
                                    unsigned short* __restrict__ out0,
                                    const float* __restrict__ in1,
                                    unsigned short* __restrict__ out1, int R,
                                    int C, int ZSPLIT) {
  __shared__ float tile[32][33];
  const int z = blockIdx.z;
  const float* in = (z < ZSPLIT) ? in0 : in1;
  unsigned short* out = (z < ZSPLIT) ? out0 : out1;
  const int zl = (z < ZSPLIT) ? z : z - ZSPLIT;
  const size_t lo = (size_t)zl * R * C;
  const int x = blockIdx.x * 32 + threadIdx.x;
#pragma unroll
  for (int i = threadIdx.y; i < 32; i += 8) {
    const int y = blockIdx.y * 32 + i;
    tile[i][threadIdx.x] = in[lo + (size_t)y * C + x];
  }
  __syncthreads();
  const int ox = blockIdx.y * 32 + threadIdx.x;
#pragma unroll
  for (int i = threadIdx.y; i < 32; i += 8) {
    const int oy = blockIdx.x * 32 + i;
    out[lo + (size_t)oy * R + ox] = f2bf(tile[threadIdx.x][i]);
  }
}

// bf16 [R][C] -> bf16 [C][R]  (fallback xT path only)
__global__ void transpose_u16(const unsigned short* __restrict__ in,
                              unsigned short* __restrict__ out, int R, int C) {
  __shared__ unsigned short tile[32][33];
  const int x = blockIdx.x * 32 + threadIdx.x;
#pragma unroll
  for (int i = threadIdx.y; i < 32; i += 8) {
    const int y = blockIdx.y * 32 + i;
    tile[i][threadIdx.x] = in[(size_t)y * C + x];
  }
  __syncthreads();
  const int ox = blockIdx.y * 32 + threadIdx.x;
#pragma unroll
  for (int i = threadIdx.y; i < 32; i += 8) {
    const int oy = blockIdx.x * 32 + i;
    out[(size_t)oy * R + ox] = tile[threadIdx.x][i];
  }
}

// causal softmax over sum of 2 fp32 partial slices; row staged in LDS.
__global__ __launch_bounds__(256) void softmax_split2(
    const float* __restrict__ p0, const float* __restrict__ p1,
    unsigned short* __restrict__ P, int n) {
  __shared__ float srow[NC];
  __shared__ float sred[4];
  const int i = blockIdx.x;
  const int valid = i + 1;
  const int wlimit = (i & ~127) + 128;
  const int t = threadIdx.x;
  const int wid = t >> 6, lane = t & 63;
  const size_t ro = (size_t)i * n;
  for (int j = t; j < valid; j += 256) srow[j] = p0[ro + j] + p1[ro + j];
  __syncthreads();

  float m = -3.0e38f;
  for (int j = t; j < valid; j += 256) m = fmaxf(m, srow[j]);
#pragma unroll
  for (int o = 32; o > 0; o >>= 1) m = fmaxf(m, __shfl_xor(m, o, 64));
  if (lane == 0) sred[wid] = m;
  __syncthreads();
  m = fmaxf(fmaxf(sred[0], sred[1]), fmaxf(sred[2], sred[3]));
  __syncthreads();

  float s = 0.f;
  for (int j = t; j < valid; j += 256) s += __expf(srow[j] - m);
#pragma unroll
  for (int o = 32; o > 0; o >>= 1) s += __shfl_xor(s, o, 64);
  if (lane == 0) sred[wid] = s;
  __syncthreads();
  s = sred[0] + sred[1] + sred[2] + sred[3];
  const float inv = 1.0f / s;

  unsigned short* prow = P + ro;
  for (int j = t; j < wlimit; j += 256)
    prow[j] = (j < valid) ? f2bf(__expf(srow[j] - m) * inv) : (unsigned short)0;
}

// fallback (non-split) softmax
__global__ __launch_bounds__(256) void softmax_causal(
    const float* __restrict__ S, unsigned short* __restrict__ P, int n) {
  __shared__ float srow[NC];
  __shared__ float sred[4];
  const int i = blockIdx.x;
  const int valid = i + 1;
  const int t = threadIdx.x;
  const int wid = t >> 6, lane = t & 63;
  const size_t ro = (size_t)i * n;
  for (int j = t; j < valid; j += 256) srow[j] = S[ro + j];
  __syncthreads();
  float m = -3.0e38f;
  for (int j = t; j < valid; j += 256) m = fmaxf(m, srow[j]);
#pragma unroll
  for (int o = 32; o > 0; o >>= 1) m = fmaxf(m, __shfl_xor(m, o, 64));
  if (lane == 0) sred[wid] = m;
  __syncthreads();
  m = fmaxf(fmaxf(sred[0], sred[1]), fmaxf(sred[2], sred[3]));
  __syncthreads();
  float s = 0.f;
  for (int j = t; j < valid; j += 256) s += __expf(srow[j] - m);
#pragma unroll
  for (int o = 32; o > 0; o >>= 1) s += __shfl_xor(s, o, 64);
  if (lane == 0) sred[wid] = s;
  __syncthreads();
  s = sred[0] + sred[1] + sred[2] + sred[3];
  const float inv = 1.0f / s;
  unsigned short* prow = P + ro;
  for (int j = t; j < n; j += 256)
    prow[j] = (j < valid) ? f2bf(__expf(srow[j] - m) * inv) : (unsigned short)0;
}

// PV reduce with causal slice skip
__global__ __launch_bounds__(256) void reduce_pv_causal(
    const float* __restrict__ part, unsigned short* __restrict__ out, size_t n,
    size_t stride) {
  const size_t i = ((size_t)blockIdx.x * 256 + threadIdx.x) * 4;
  if (i >= n) return;
  const int row = (int)(i >> 10);  // i / DM
  const int nsl = (row >> 9) + 1;  // 1..4 contributing slices
  float4 v = *reinterpret_cast<const float4*>(part + i);
  for (int s = 1; s < nsl; s++) {
    const float4 w = *reinterpret_cast<const float4*>(part + (size_t)s * stride + i);
    v.x += w.x; v.y += w.y; v.z += w.z; v.w += w.w;
  }
  u16x4_t o;
  o[0] = f2bf(v.x); o[1] = f2bf(v.y); o[2] = f2bf(v.z); o[3] = f2bf(v.w);
  *reinterpret_cast<u16x4_t*>(out + i) = o;
}

// x += b_down + sum4(down_part) + sum2(ov_part); xb = bf16(x); xT = xb^T
// (fallback split path)
__global__ __launch_bounds__(256) void residual_tiled(
    float* __restrict__ x, unsigned short* __restrict__ xb,
    unsigned short* __restrict__ xT, const float* __restrict__ dp,
    const float* __restrict__ op, const float* __restrict__ bd) {
  __shared__ unsigned short tile[32][33];
  const int tx = threadIdx.x;  // 0..7
  const int ty = threadIdx.y;  // 0..31
  const int col0 = blockIdx.x * 32;
  const int row0 = blockIdx.y * 32;
  const size_t n = (size_t)NC * DM;
  const int row = row0 + ty;
  const int col = col0 + tx * 4;
  const size_t idx = (size_t)row * DM + col;

  float4 v = *reinterpret_cast<const float4*>(x + idx);
  const float4 b = *reinterpret_cast<const float4*>(bd + col);
  v.x += b.x; v.y += b.y; v.z += b.z; v.w += b.w;
#pragma unroll
  for (int s = 0; s < 4; s++) {
    const float4 w = *reinterpret_cast<const float4*>(dp + (size_t)s * n + idx);
    v.x += w.x; v.y += w.y; v.z += w.z; v.w += w.w;
  }
#pragma unroll
  for (int s = 0; s < 2; s++) {
    const float4 w = *reinterpret_cast<const float4*>(op + (size_t)s * n + idx);
    v.x += w.x; v.y += w.y; v.z += w.z; v.w += w.w;
  }
  *reinterpret_cast<float4*>(x + idx) = v;
  u16x4_t o;
  o[0] = f2bf(v.x); o[1] = f2bf(v.y); o[2] = f2bf(v.z); o[3] = f2bf(v.w);
  *reinterpret_cast<u16x4_t*>(xb + idx) = o;
  tile[ty][tx * 4 + 0] = o[0];
  tile[ty][tx * 4 + 1] = o[1];
  tile[ty][tx * 4 + 2] = o[2];
  tile[ty][tx * 4 + 3] = o[3];
  __syncthreads();

  const int t = ty * 8 + tx;
  const int wc = t >> 5;
  const int wr = t & 31;
#pragma unroll
  for (int j = 0; j < 4; j++) {
    const int c = wc + j * 8;
    xT[(size_t)(col0 + c) * NC + row0 + wr] = tile[wr][c];
  }
}

// fallback residual
__global__ __launch_bounds__(256) void residual_kernel(
    float* __restrict__ x, const float* __restrict__ hd,
    const float* __restrict__ attn, unsigned short* __restrict__ xb, int n) {
  const int idx = blockIdx.x * 256 + threadIdx.x;
  if (idx < n) {
    const float v = x[idx] + hd[idx] + attn[idx];
    x[idx] = v;
    xb[idx] = f2bf(v);
  }
}

// ---------------------------------------------------------------------------
extern "C" void kernel_launch(void* const* d_in, const int* in_sizes, int n_in,
                              void* d_out, int out_size, void* d_ws,
                              size_t ws_size, hipStream_t stream) {
  const int* tokens = (const int*)d_in[0];
  const float* tok_emb = (const float*)d_in[1];
  const float* pos_emb = (const float*)d_in[2];
  const float* wqk = (const float*)d_in[3];
  const float* wov = (const float*)d_in[4];
  const float* w_up = (const float*)d_in[5];
  const float* b_up = (const float*)d_in[6];
  const float* w_down = (const float*)d_in[7];
  const float* b_down = (const float*)d_in[8];
  float* logits = (float*)d_out;

  uint8_t* base = (uint8_t*)d_ws;
  size_t used = 0;
  auto alloc = [&](size_t bytes) -> void* {
    const size_t ab = (bytes + 255) & ~(size_t)255;
    if (used + ab > ws_size) return (void*)0;
    void* r = base + used;
    used += ab;
    return r;
  };

  // mandatory
  float* x = (float*)alloc((size_t)NC * DM * 4);
  unsigned short* xb = (unsigned short*)alloc((size_t)NC * DM * 2);
  unsigned short* h1 = (unsigned short*)alloc((size_t)NC * DH * 2);
  unsigned short* qb = (unsigned short*)alloc((size_t)NC * DM * 2);
  unsigned short* Pb = (unsigned short*)alloc((size_t)NC * NC * 2);
  unsigned short* xT = (unsigned short*)alloc((size_t)NC * DM * 2);
  unsigned short* ab = (unsigned short*)alloc((size_t)NC * DM * 2);
  unsigned short* wqkT = (unsigned short*)alloc((size_t)NL * DM * DM * 2);
  unsigned short* wovT = (unsigned short*)alloc((size_t)NL * DM * DM * 2);
  float* hd = (float*)alloc((size_t)NC * DM * 4);
  float* attn = (float*)alloc((size_t)NC * DM * 4);
  float* scores = (float*)alloc((size_t)NC * NC * 4);
  // optional tiers
  float* dpart = (float*)alloc((size_t)4 * NC * DM * 4);   // 32 MB (4 slices)
  float* opart = (float*)alloc((size_t)2 * NC * DM * 4);   // 16 MB
  float* pool = (float*)alloc((size_t)2 * NC * NC * 4);    // 32 MB
  unsigned short* wupB = (unsigned short*)alloc((size_t)NL * DH * DM * 2);    // 64 MB
  unsigned short* wdownB = (unsigned short*)alloc((size_t)NL * DM * DH * 2);  // 64 MB
  unsigned short* tokB = (unsigned short*)alloc((size_t)DV * DM * 2);         // 62.5 MB

  const bool split_en = (dpart && opart && pool);
  const bool have_wbf = (wupB && wdownB);
  const bool have_tok = (tokB != 0);
  const bool fused_en = split_en && have_wbf;

  const dim3 tb(32, 8);
  if (fused_en) {
    // embed + layer-0 wqk/wov transpose in one launch; layers 1..7
    // transposed in-loop; xT produced as a fused_up_q(0) tail segment.
    embed_tr<<<NC + 256, 256, 0, stream>>>(tokens, tok_emb, pos_emb, x, xb,
                                           wqk, wqkT, wov, wovT);
  } else {
    transpose_cast_dual<<<dim3(DM / 32, DM / 32, 2 * NL), tb, 0, stream>>>(
        wqk, wqkT, wov, wovT, DM, DM, NL);
    if (have_wbf && have_tok)
      cast3_f32_bf16<<<3 * 2048, 256, 0, stream>>>(
          w_up, wupB, (size_t)NL * DH * DM, w_down, wdownB, (size_t)NL * DM * DH,
          tok_emb, tokB, (size_t)DV * DM, 2048);
    embed_kernel<<<NC, 256, 0, stream>>>(tokens, tok_emb, pos_emb, x, xb);
    transpose_u16<<<dim3(DM / 32, NC / 32), tb, 0, stream>>>(xb, xT, NC, DM);
  }

  const size_t nMD = (size_t)NC * DM;
  const size_t tokQ = (size_t)DV * DM / (2 * NL);  // 2,048,000 (mult of 8)

  for (int l = 0; l < NL; l++) {
    if (fused_en) {
      // cast work for next layer's weights + this layer's tok_emb slice
      const bool nw = (l + 1 < NL);
      const float* u0s = nw ? w_up + (size_t)(l + 1) * DH * DM : nullptr;
      unsigned short* u0d = nw ? wupB + (size_t)(l + 1) * DH * DM : nullptr;
      const size_t u0n = nw ? (size_t)DH * DM : 0;
      const float* d0s = nw ? w_down + (size_t)(l + 1) * DM * DH : nullptr;
      unsigned short* d0d = nw ? wdownB + (size_t)(l + 1) * DM * DH : nullptr;
      const size_t d0n = nw ? (size_t)DM * DH : 0;
      const float* t0s = have_tok ? tok_emb + (size_t)l * 2 * tokQ : nullptr;
      unsigned short* t0d = have_tok ? tokB + (size_t)l * 2 * tokQ : nullptr;
      const float* t1s = have_tok ? tok_emb + (size_t)l * 2 * tokQ + tokQ : nullptr;
      unsigned short* t1d = have_tok ? tokB + (size_t)l * 2 * tokQ + tokQ : nullptr;
      const size_t tn = have_tok ? tokQ : 0;
      // next-layer wqk/wov transpose (tail segment of fused_up_q)
      const float* tr0s = nw ? wqk + (size_t)(l + 1) * DM * DM : nullptr;
      unsigned short* tr0d = nw ? wqkT + (size_t)(l + 1) * DM * DM : nullptr;
      const float* tr1s = nw ? wov + (size_t)(l + 1) * DM * DM : nullptr;
      unsigned short* tr1d = nw ? wovT + (size_t)(l + 1) * DM * DM : nullptr;

      // ---- up + q(full) + cast + transpose (+ xT tail at l==0) ----
      if (l == 0)
        fused_up_q<true><<<2304, 256, 0, stream>>>(
            xb, w_up, b_up, h1, wqkT, qb, u0s, u0d, u0n, t0s, t0d, tn,
            tr0s, tr0d, tr1s, tr1d, xT);
      else
        fused_up_q<false><<<2048, 256, 0, stream>>>(
            xb, wupB + (size_t)l * DH * DM, b_up + (size_t)l * DH, h1,
            wqkT + (size_t)l * DM * DM, qb, u0s, u0d, u0n, t0s, t0d, tn,
            tr0s, tr0d, tr1s, tr1d, xT);
      // ---- down(split4) + scores(split2) + cast in one launch ----
      if (l == 0)
        fused_down_sc<true><<<2560, 256, 0, stream>>>(
            h1, w_down, dpart, qb, xb, pool, d0s, d0d, d0n, t1s, t1d, tn);
      else
        fused_down_sc<false><<<2560, 256, 0, stream>>>(
            h1, wdownB + (size_t)l * DM * DH, dpart, qb, xb, pool, d0s, d0d,
            d0n, t1s, t1d, tn);
      // ---- softmax over summed score slices ----
      softmax_split2<<<NC, 256, 0, stream>>>(pool, pool + (size_t)NC * NC, Pb, NC);
      // ---- attn partials a = P @ x  [2048,1024], K=2048 split 4 causal ----
      gemm_nt<64, false, true, false, true, false, false, false>
          <<<dim3(DM / 64, NC / 128, 4), 256, 0, stream>>>(
              Pb, xT, nullptr, pool, NC, DM, NC, NC / 4);
      reduce_pv_causal<<<(nMD / 4 + 255) / 256, 256, 0, stream>>>(pool, ab, nMD, nMD);
      // ---- ov + residual fused: x,xb,xT updated in one launch ----
      gemm_ov_res<<<dim3(DM / 64, NC / 128), 256, 0, stream>>>(
          ab, wovT + (size_t)l * DM * DM, x, xb, xT, dpart,
          b_down + (size_t)l * DM);
    } else {
      gemm_nt<64, true, false, false, false, true, true, true>
          <<<dim3(DH / 64, NC / 128), 256, 0, stream>>>(
              xb, w_up + (size_t)l * DH * DM, b_up + (size_t)l * DH, h1, NC, DH, DM, DM);
      gemm_nt<64, true, false, false, false, true, false, false>
          <<<dim3(DM / 64, NC / 128), 256, 0, stream>>>(
              h1, w_down + (size_t)l * DM * DH, b_down + (size_t)l * DM, hd, NC, DM, DH, DH);
      gemm_nt<64, false, false, false, false, false, false, true>
          <<<dim3(DM / 64, NC / 128), 256, 0, stream>>>(
              xb, wqkT + (size_t)l * DM * DM, nullptr, qb, NC, DM, DM, DM);

      if (split_en) {
        gemm_nt<64, false, true, true, false, false, false, false>
            <<<dim3(NC / 64, NC / 128, 2), 256, 0, stream>>>(
                qb, xb, nullptr, pool, NC, NC, DM, DM / 2);
        softmax_split2<<<NC, 256, 0, stream>>>(pool, pool + (size_t)NC * NC, Pb, NC);
        gemm_nt<64, false, true, false, true, false, false, false>
            <<<dim3(DM / 64, NC / 128, 4), 256, 0, stream>>>(
                Pb, xT, nullptr, pool, NC, DM, NC, NC / 4);
        reduce_pv_causal<<<(nMD / 4 + 255) / 256, 256, 0, stream>>>(pool, ab, nMD, nMD);
        gemm_nt<64, false, true, false, false, false, false, false>
            <<<dim3(DM / 64, NC / 128, 2), 256, 0, stream>>>(
                ab, wovT + (size_t)l * DM * DM, nullptr, opart, NC, DM, DM, DM / 2);
        residual_tiled<<<dim3(DM / 32, NC / 32), dim3(8, 32), 0, stream>>>(
            x, xb, xT, dpart, opart, b_down + (size_t)l * DM);
      } else {
        gemm_nt<64, false, false, true, false, false, false, false>
            <<<dim3(NC / 64, NC / 128), 256, 0, stream>>>(
                qb, xb, nullptr, scores, NC, NC, DM, DM);
        softmax_causal<<<NC, 256, 0, stream>>>(scores, Pb, NC);
        transpose_u16<<<dim3(DM / 32, NC / 32), tb, 0, stream>>>(xb, xT, NC, DM);
        gemm_nt<64, false, false, false, true, false, false, true>
            <<<dim3(DM / 64, NC / 128), 256, 0, stream>>>(
                Pb, xT, nullptr, ab, NC, DM, NC, NC);
        gemm_nt<64, false, false, false, false, false, false, false>
            <<<dim3(DM / 64, NC / 128), 256, 0, stream>>>(
                ab, wovT + (size_t)l * DM * DM, nullptr, attn, NC, DM, DM, DM);
        residual_kernel<<<(int)(nMD / 256), 256, 0, stream>>>(x, hd, attn, xb, (int)nMD);
      }
    }
  }

  // ---- logits = x @ tok_emb^T  [2048,32000] fp32, BN=64 (proven ~204us) ----
  if (have_tok && fused_en)
    gemm_nt<64, false, false, false, false, false, false, false>
        <<<dim3(DV / 64, NC / 128), 256, 0, stream>>>(
            xb, tokB, nullptr, logits, NC, DV, DM, DM);
  else if (have_tok && have_wbf)
    gemm_nt<64, false, false, false, false, false, false, false>
        <<<dim3(DV / 64, NC / 128), 256, 0, stream>>>(
            xb, tokB, nullptr, logits, NC, DV, DM, DM);
  else
    gemm_nt<64, true, false, false, false, false, false, false>
        <<<dim3(DV / 64, NC / 128), 256, 0, stream>>>(
            xb, tok_emb, nullptr, logits, NC, DV, DM, DM);
}